// Round 3
// baseline (115.329 us; speedup 1.0000x reference)
//
#include <hip/hip_runtime.h>

// JSD(P, W) for shape (8192, 4096) fp32:
//   M = 0.5*(W+P)
//   result = 0.5 * ( sum_{w>0,m>0} w*log2(w/m) + sum_{p>0,m>0} p*log2(p/m) ) / 8192
//
// Memory-bound streaming reduction: 268 MB read -> one scalar (5.7 TB/s achieved).
// R3 change: single-kernel "last block done" finish (rocPRIM decoupled pattern)
// to remove the ~2-3 us second-dispatch tail. Deterministic: the last block
// reduces partials in fixed index order regardless of completion order.

#define NBLOCKS 2048

__device__ __forceinline__ float jsd_term(float p, float w) {
    float m  = 0.5f * (w + p);
    float lm = __log2f(m);           // -inf when m==0, discarded by selects below
    float tw = (w > 0.0f && m > 0.0f) ? w * (__log2f(w) - lm) : 0.0f;
    float tp = (p > 0.0f && m > 0.0f) ? p * (__log2f(p) - lm) : 0.0f;
    return tw + tp;
}

__global__ void __launch_bounds__(256) jsd_fused_kernel(
    const float4* __restrict__ P4, const float4* __restrict__ W4,
    float* __restrict__ partials, unsigned int* __restrict__ counter,
    float* __restrict__ out, int n4) {
    float acc = 0.0f;
    int idx    = blockIdx.x * blockDim.x + threadIdx.x;
    int stride = gridDim.x * blockDim.x;
    for (int i = idx; i < n4; i += stride) {
        float4 p = P4[i];
        float4 w = W4[i];
        acc += jsd_term(p.x, w.x);
        acc += jsd_term(p.y, w.y);
        acc += jsd_term(p.z, w.z);
        acc += jsd_term(p.w, w.w);
    }
    // wave (64-lane) reduction
    #pragma unroll
    for (int off = 32; off > 0; off >>= 1)
        acc += __shfl_down(acc, off, 64);
    __shared__ float smem[4];  // 256 threads = 4 waves
    int wave = threadIdx.x >> 6;
    if ((threadIdx.x & 63) == 0) smem[wave] = acc;
    __syncthreads();

    __shared__ int is_last;
    if (threadIdx.x == 0) {
        partials[blockIdx.x] = smem[0] + smem[1] + smem[2] + smem[3];
        __threadfence();  // make partial visible device-wide before signaling
        unsigned int prev = atomicAdd(counter, 1u);
        is_last = (prev == (unsigned int)(gridDim.x - 1)) ? 1 : 0;
    }
    __syncthreads();
    if (is_last) {
        __threadfence();  // acquire: see all other blocks' partials
        double dacc = 0.0;
        for (int i = threadIdx.x; i < (int)gridDim.x; i += blockDim.x)
            dacc += (double)partials[i];
        #pragma unroll
        for (int off = 32; off > 0; off >>= 1)
            dacc += __shfl_down(dacc, off, 64);
        __shared__ double dsm[4];
        if ((threadIdx.x & 63) == 0) dsm[wave] = dacc;
        __syncthreads();
        if (threadIdx.x == 0) {
            double total = dsm[0] + dsm[1] + dsm[2] + dsm[3];
            out[0] = (float)(total * (0.5 / 8192.0));
            *counter = 0u;  // self-reset for next replay
        }
    }
}

extern "C" void kernel_launch(void* const* d_in, const int* in_sizes, int n_in,
                              void* d_out, int out_size, void* d_ws, size_t ws_size,
                              hipStream_t stream) {
    const float* P = (const float*)d_in[0];
    const float* W = (const float*)d_in[1];
    float* out = (float*)d_out;
    float* partials = (float*)d_ws;
    unsigned int* counter = (unsigned int*)((char*)d_ws + NBLOCKS * sizeof(float));

    const long long n = (long long)in_sizes[0];    // 8192*4096 = 33554432
    const int n4 = (int)(n / 4);                   // divisible

    // zero the completion counter (graph-capture-safe async memset)
    hipMemsetAsync(counter, 0, sizeof(unsigned int), stream);

    jsd_fused_kernel<<<NBLOCKS, 256, 0, stream>>>(
        (const float4*)P, (const float4*)W, partials, counter, out, n4);
}

// Round 4
// 46.222 us; speedup vs baseline: 2.4951x; 2.4951x over previous
//
#include <hip/hip_runtime.h>

// JSD(P, W) for shape (8192, 4096) fp32:
//   M = 0.5*(W+P)
//   result = 0.5 * ( sum_{w>0,m>0} w*log2(w/m) + sum_{p>0,m>0} p*log2(p/m) ) / 8192
//
// Memory-bound streaming reduction: 268 MB read -> one scalar.
// R4: revert R3's fused-atomic finish (2x regression: agent-scope fence
// poisoned streaming). Two-kernel structure from R1 + block-contiguous
// chunking for DRAM/L3 locality: each block owns a contiguous chunk,
// each wave streams sequential 1KB lines.

#define NBLOCKS 2048
#define NTHREADS 256

__device__ __forceinline__ float jsd_term(float p, float w) {
    float m  = 0.5f * (w + p);
    float lm = __log2f(m);           // -inf when m==0, discarded by selects below
    float tw = (w > 0.0f && m > 0.0f) ? w * (__log2f(w) - lm) : 0.0f;
    float tp = (p > 0.0f && m > 0.0f) ? p * (__log2f(p) - lm) : 0.0f;
    return tw + tp;
}

__global__ void __launch_bounds__(NTHREADS) jsd_partial_kernel(
    const float4* __restrict__ P4, const float4* __restrict__ W4,
    float* __restrict__ partials, int n4) {
    // block-contiguous partition: block b owns [b*chunk, (b+1)*chunk)
    const int chunk = n4 / NBLOCKS;              // 4096 float4s (n4 divisible)
    const int base  = blockIdx.x * chunk;
    const int end   = base + chunk;

    float acc = 0.0f;
    for (int i = base + threadIdx.x; i < end; i += NTHREADS) {
        float4 p = P4[i];
        float4 w = W4[i];
        acc += jsd_term(p.x, w.x);
        acc += jsd_term(p.y, w.y);
        acc += jsd_term(p.z, w.z);
        acc += jsd_term(p.w, w.w);
    }

    // wave (64-lane) reduction
    #pragma unroll
    for (int off = 32; off > 0; off >>= 1)
        acc += __shfl_down(acc, off, 64);
    __shared__ float smem[4];  // 256 threads = 4 waves
    int wave = threadIdx.x >> 6;
    if ((threadIdx.x & 63) == 0) smem[wave] = acc;
    __syncthreads();
    if (threadIdx.x == 0)
        partials[blockIdx.x] = smem[0] + smem[1] + smem[2] + smem[3];
}

__global__ void __launch_bounds__(256) jsd_finish_kernel(
    const float* __restrict__ partials, int n, float* __restrict__ out) {
    double acc = 0.0;
    for (int i = threadIdx.x; i < n; i += blockDim.x)
        acc += (double)partials[i];
    #pragma unroll
    for (int off = 32; off > 0; off >>= 1)
        acc += __shfl_down(acc, off, 64);
    __shared__ double smem[4];
    int wave = threadIdx.x >> 6;
    if ((threadIdx.x & 63) == 0) smem[wave] = acc;
    __syncthreads();
    if (threadIdx.x == 0) {
        double total = smem[0] + smem[1] + smem[2] + smem[3];
        out[0] = (float)(total * (0.5 / 8192.0));
    }
}

extern "C" void kernel_launch(void* const* d_in, const int* in_sizes, int n_in,
                              void* d_out, int out_size, void* d_ws, size_t ws_size,
                              hipStream_t stream) {
    const float* P = (const float*)d_in[0];
    const float* W = (const float*)d_in[1];
    float* out = (float*)d_out;
    float* partials = (float*)d_ws;

    const long long n = (long long)in_sizes[0];    // 8192*4096 = 33554432
    const int n4 = (int)(n / 4);                   // 8388608, divisible by 2048

    jsd_partial_kernel<<<NBLOCKS, NTHREADS, 0, stream>>>(
        (const float4*)P, (const float4*)W, partials, n4);
    jsd_finish_kernel<<<1, 256, 0, stream>>>(partials, NBLOCKS, out);
}